// Round 1
// baseline (927.257 us; speedup 1.0000x reference)
//
#include <hip/hip_runtime.h>
#include <hip/hip_bf16.h>
#include <stdint.h>

// FGNN: per-pixel mask-selected complex matmul + per-ring mean + combine.
// y = x @ (mask==0 ? W1 : W2)  (complex)  -- computed via delta trick:
//     y = (x*u) @ (W1-W2) + x @ W2   so each image element is read once.
// s = ring-mean of y over mask==0 pixels (denominator = full ring count)
// out = u ? 0.5*(y+s) : (y-s), layout [512,512,128,2] (re/im interleaved).

#define WH 512
#define NPIX (WH * WH)
#define NF 128
#define NRINGS 363

typedef unsigned short u16;
typedef __attribute__((ext_vector_type(8))) short short8;
typedef __attribute__((ext_vector_type(4))) float floatx4;

__device__ __forceinline__ u16 f2bf(float x) {
    uint32_t u = __float_as_uint(x);
    uint32_t r = (u + 0x7FFFu + ((u >> 16) & 1u)) >> 16;  // RNE
    return (u16)r;
}
__device__ __forceinline__ uint32_t pk(float a, float b) {
    return (uint32_t)f2bf(a) | ((uint32_t)f2bf(b) << 16);
}
__device__ __forceinline__ short8 negbf(short8 v) {
    union { short8 s; uint32_t u[4]; } x;
    x.s = v;
    x.u[0] ^= 0x80008000u; x.u[1] ^= 0x80008000u;
    x.u[2] ^= 0x80008000u; x.u[3] ^= 0x80008000u;
    return x.s;
}
__device__ __forceinline__ floatx4 mfma16(short8 a, short8 b, floatx4 c) {
    return __builtin_amdgcn_mfma_f32_16x16x32_bf16(a, b, c, 0, 0, 0);
}

// ---------------- K0: build bf16 transposed weights [n][k] in ws ----------
// bt layout: mat 0 = W1r-W2r, 1 = W2r, 2 = W1i-W2i, 3 = W2i; each 128x128.
__global__ void k_build_bt(const float* __restrict__ w1r, const float* __restrict__ w1i,
                           const float* __restrict__ w2r, const float* __restrict__ w2i,
                           u16* __restrict__ bt) {
    int n = blockIdx.x, k = threadIdx.x;   // grid 128, block 128
    int src = k * NF + n;
    float a1r = w1r[src], a1i = w1i[src], a2r = w2r[src], a2i = w2i[src];
    int d = n * NF + k;
    bt[0 * 16384 + d] = f2bf(a1r - a2r);
    bt[1 * 16384 + d] = f2bf(a2r);
    bt[2 * 16384 + d] = f2bf(a1i - a2i);
    bt[3 * 16384 + d] = f2bf(a2i);
}

// ---------------- K1: masked complex GEMM -> y into d_out -----------------
// block tile 128 px x 128 f, 4 waves (wave = 32 px x 128 f), K=128, BK=32.
// LDS rows padded to 40 ushorts (80 B): conflict-free ds_read_b128.
#define BROW 40
#define LDS_AR 0
#define LDS_AI 5120
#define LDS_B  10240   // + mat*5120

__global__ __launch_bounds__(256, 2) void k_gemm(
    const float* __restrict__ xr, const float* __restrict__ xi,
    const int* __restrict__ mask, const u16* __restrict__ bt,
    float* __restrict__ out)
{
    __shared__ u16 lds[30720];  // 60 KB
    const int t = threadIdx.x;
    const int pbase = blockIdx.x * 128;
    const int w = t >> 6, lane = t & 63;
    const int quad = lane >> 4, l16 = lane & 15;

    floatx4 accRe[2][8], accIm[2][8];
#pragma unroll
    for (int mi = 0; mi < 2; mi++)
#pragma unroll
        for (int ni = 0; ni < 8; ni++) {
            accRe[mi][ni] = (floatx4)0.0f;
            accIm[mi][ni] = (floatx4)0.0f;
        }

    // per-lane row masks for the A fragments (row is lane-uniform in a frag)
    bool uu[2];
    uu[0] = (mask[pbase + w * 32 + l16] == 0);
    uu[1] = (mask[pbase + w * 32 + 16 + l16] == 0);

    // staging mapping: thread -> (row, half of 32-k window)
    const int sr = t >> 1, sh = t & 1;
    const float4* xr4 = (const float4*)(xr + (size_t)(pbase + sr) * NF);
    const float4* xi4 = (const float4*)(xi + (size_t)(pbase + sr) * NF);

    for (int kw = 0; kw < 4; kw++) {
        if (kw) __syncthreads();
        // ---- stage A (unmasked re/im), fp32 -> bf16 ----
        {
            int qb = kw * 8 + sh * 4;
            float4 r0 = xr4[qb], r1 = xr4[qb + 1], r2 = xr4[qb + 2], r3 = xr4[qb + 3];
            float4 i0 = xi4[qb], i1 = xi4[qb + 1], i2 = xi4[qb + 2], i3 = xi4[qb + 3];
            uint4 a, b;
            a.x = pk(r0.x, r0.y); a.y = pk(r0.z, r0.w); a.z = pk(r1.x, r1.y); a.w = pk(r1.z, r1.w);
            b.x = pk(r2.x, r2.y); b.y = pk(r2.z, r2.w); b.z = pk(r3.x, r3.y); b.w = pk(r3.z, r3.w);
            *(uint4*)&lds[LDS_AR + sr * BROW + sh * 16]     = a;
            *(uint4*)&lds[LDS_AR + sr * BROW + sh * 16 + 8] = b;
            a.x = pk(i0.x, i0.y); a.y = pk(i0.z, i0.w); a.z = pk(i1.x, i1.y); a.w = pk(i1.z, i1.w);
            b.x = pk(i2.x, i2.y); b.y = pk(i2.z, i2.w); b.z = pk(i3.x, i3.y); b.w = pk(i3.z, i3.w);
            *(uint4*)&lds[LDS_AI + sr * BROW + sh * 16]     = a;
            *(uint4*)&lds[LDS_AI + sr * BROW + sh * 16 + 8] = b;
        }
        // ---- stage B window (already bf16 in ws, L2-hot) ----
#pragma unroll
        for (int q = 0; q < 8; q++) {
            int fi = q * 256 + t;            // 0..2047
            int mat = fi >> 9;
            int wi = fi & 511;
            int n = wi >> 2, kc = wi & 3;
            uint4 v = *(const uint4*)(bt + mat * 16384 + n * 128 + kw * 32 + kc * 8);
            *(uint4*)&lds[LDS_B + mat * 5120 + n * BROW + kc * 8] = v;
        }
        __syncthreads();

        // ---- compute ----
        short8 ar[2], ai[2], aru[2], aiu[2];
#pragma unroll
        for (int mi = 0; mi < 2; mi++) {
            int r = w * 32 + mi * 16 + l16;
            ar[mi] = *(short8*)&lds[LDS_AR + r * BROW + quad * 8];
            ai[mi] = *(short8*)&lds[LDS_AI + r * BROW + quad * 8];
            aru[mi] = uu[mi] ? ar[mi] : (short8)0;
            aiu[mi] = uu[mi] ? ai[mi] : (short8)0;
        }
#pragma unroll
        for (int ni = 0; ni < 8; ni++) {
            int nrow = ni * 16 + l16;
            short8 bDr = *(short8*)&lds[LDS_B + 0 * 5120 + nrow * BROW + quad * 8];
            short8 b2r = *(short8*)&lds[LDS_B + 1 * 5120 + nrow * BROW + quad * 8];
            short8 bDi = *(short8*)&lds[LDS_B + 2 * 5120 + nrow * BROW + quad * 8];
            short8 b2i = *(short8*)&lds[LDS_B + 3 * 5120 + nrow * BROW + quad * 8];
            short8 bDin = negbf(bDi), b2in = negbf(b2i);
#pragma unroll
            for (int mi = 0; mi < 2; mi++) {
                accRe[mi][ni] = mfma16(aru[mi], bDr,  accRe[mi][ni]);
                accRe[mi][ni] = mfma16(ar[mi],  b2r,  accRe[mi][ni]);
                accRe[mi][ni] = mfma16(aiu[mi], bDin, accRe[mi][ni]);
                accRe[mi][ni] = mfma16(ai[mi],  b2in, accRe[mi][ni]);
                accIm[mi][ni] = mfma16(aru[mi], bDi,  accIm[mi][ni]);
                accIm[mi][ni] = mfma16(ar[mi],  b2i,  accIm[mi][ni]);
                accIm[mi][ni] = mfma16(aiu[mi], bDr,  accIm[mi][ni]);
                accIm[mi][ni] = mfma16(ai[mi],  b2r,  accIm[mi][ni]);
            }
        }
    }

    // ---- epilogue: interleaved [p][f][re,im] float2 stores ----
#pragma unroll
    for (int mi = 0; mi < 2; mi++)
#pragma unroll
        for (int ni = 0; ni < 8; ni++)
#pragma unroll
            for (int r = 0; r < 4; r++) {
                int p = pbase + w * 32 + mi * 16 + quad * 4 + r;
                int f = ni * 16 + l16;
                float2 v;
                v.x = accRe[mi][ni][r];
                v.y = accIm[mi][ni][r];
                *(float2*)(out + (size_t)p * 256 + f * 2) = v;
            }
}

// ---------------- K2: per-ring sums (u-pixels) + full counts --------------
// block = (ring R, 128-row chunk); 256 threads each own one of 256 columns.
// j-intervals per row from exact integer bounds R^2 <= x^2+y^2 < (R+1)^2.
__global__ void k_ringsum(const float* __restrict__ y, const int* __restrict__ mask,
                          float* __restrict__ rs, float* __restrict__ cnt)
{
    const int R = blockIdx.x;
    const int t = threadIdx.x;
    const int row0 = blockIdx.y * 128;
    const int R2 = R * R, R12 = (R + 1) * (R + 1);
    float acc = 0.0f;
    int count = 0;
    for (int i = row0; i < row0 + 128; i++) {
        int x = i - 256;
        int x2 = x * x;
        int hi2 = R12 - x2;
        if (hi2 <= 0) continue;
        int lo2 = R2 - x2;
        int a = 0;
        if (lo2 > 0) {
            a = (int)ceilf(sqrtf((float)lo2));
            while (a * a < lo2) a++;
            while (a > 0 && (a - 1) * (a - 1) >= lo2) a--;
        }
        int b = (int)ceilf(sqrtf((float)hi2));
        while (b * b < hi2) b++;
        while (b > 0 && (b - 1) * (b - 1) >= hi2) b--;
        // |y| in [a, b-1]
        int yhi = min(b - 1, 255);
        for (int yy = a; yy <= yhi; yy++) {          // y >= 0 side (incl 0)
            int p = i * 512 + (yy + 256);
            count++;
            if (mask[p] == 0) acc += y[(size_t)p * 256 + t];
        }
        int ylo = max(a, 1);
        int yhi2 = min(b - 1, 256);
        for (int yy = ylo; yy <= yhi2; yy++) {       // y < 0 side
            int p = i * 512 + (256 - yy);
            count++;
            if (mask[p] == 0) acc += y[(size_t)p * 256 + t];
        }
    }
    atomicAdd(&rs[R * 256 + t], acc);
    if (t == 0) atomicAdd(&cnt[R], (float)count);
}

// ---------------- K3: in-place finalize -----------------------------------
__global__ void k_final(const int* __restrict__ mask, const float* __restrict__ rs,
                        const float* __restrict__ cnt, float* __restrict__ out)
{
    const int t = threadIdx.x;
    const int p0 = blockIdx.x * 64;
    for (int pp = 0; pp < 64; pp++) {
        int p = p0 + pp;
        int i = p >> 9, j = p & 511;
        int x = i - 256, yy = j - 256;
        int r2 = x * x + yy * yy;
        int R = (int)sqrtf((float)r2);
        while ((R + 1) * (R + 1) <= r2) R++;
        while (R * R > r2) R--;
        float c = cnt[R];
        c = (c < 1.0f) ? 1.0f : c;
        float s = rs[R * 256 + t] / c;
        float v = out[(size_t)p * 256 + t];
        float o = (mask[p] == 0) ? 0.5f * (v + s) : (v - s);
        out[(size_t)p * 256 + t] = o;
    }
}

extern "C" void kernel_launch(void* const* d_in, const int* in_sizes, int n_in,
                              void* d_out, int out_size, void* d_ws, size_t ws_size,
                              hipStream_t stream)
{
    const float* xr  = (const float*)d_in[0];  // image_re [512,512,128]
    const float* xi  = (const float*)d_in[1];  // image_im
    const int*   msk = (const int*)d_in[2];    // mask [512,512] int32
    // d_in[3], d_in[4] = output_re/output_im zero inits (unused)
    const float* w1r = (const float*)d_in[5];
    const float* w1i = (const float*)d_in[6];
    const float* w2r = (const float*)d_in[7];
    const float* w2i = (const float*)d_in[8];
    float* out = (float*)d_out;                // [512,512,128,2] fp32

    // ws layout: rs[363*256] f32 | cnt[363] f32 | pad | bt[4*16384] bf16
    float* rs  = (float*)d_ws;
    float* cnt = rs + NRINGS * 256;
    u16*   bt  = (u16*)((char*)d_ws + 373248);

    hipMemsetAsync(d_ws, 0, (size_t)(NRINGS * 256 + NRINGS) * sizeof(float), stream);
    k_build_bt<<<dim3(128), dim3(128), 0, stream>>>(w1r, w1i, w2r, w2i, bt);
    k_gemm<<<dim3(NPIX / 128), dim3(256), 0, stream>>>(xr, xi, msk, bt, out);
    k_ringsum<<<dim3(NRINGS, 4), dim3(256), 0, stream>>>(out, msk, rs, cnt);
    k_final<<<dim3(NPIX / 64), dim3(256), 0, stream>>>(msk, rs, cnt, out);
}

// Round 2
// 902.129 us; speedup vs baseline: 1.0279x; 1.0279x over previous
//
#include <hip/hip_runtime.h>
#include <hip/hip_bf16.h>
#include <stdint.h>

// FGNN: per-pixel mask-selected complex matmul + per-ring mean + combine.
// y = x @ (mask==0 ? W1 : W2)  (complex)  -- computed via delta trick:
//     y = (x*u) @ (W1-W2) + x @ W2   so each image element is read once.
// s = ring-mean of y over mask==0 pixels (denominator = full ring count)
// out = u ? 0.5*(y+s) : (y-s), layout [512,512,128,2] (re/im interleaved).

#define WH 512
#define NPIX (WH * WH)
#define NF 128
#define NRINGS 363
#define SLAB 1664   // max pixels per ring is ~1608 (annulus pi*(2R+1) at R=255)

typedef unsigned short u16;
typedef __attribute__((ext_vector_type(8))) short short8;
typedef __attribute__((ext_vector_type(4))) float floatx4;

__device__ __forceinline__ u16 f2bf(float x) {
    uint32_t u = __float_as_uint(x);
    uint32_t r = (u + 0x7FFFu + ((u >> 16) & 1u)) >> 16;  // RNE
    return (u16)r;
}
__device__ __forceinline__ uint32_t pk(float a, float b) {
    return (uint32_t)f2bf(a) | ((uint32_t)f2bf(b) << 16);
}
__device__ __forceinline__ short8 negbf(short8 v) {
    union { short8 s; uint32_t u[4]; } x;
    x.s = v;
    x.u[0] ^= 0x80008000u; x.u[1] ^= 0x80008000u;
    x.u[2] ^= 0x80008000u; x.u[3] ^= 0x80008000u;
    return x.s;
}
__device__ __forceinline__ floatx4 mfma16(short8 a, short8 b, floatx4 c) {
    return __builtin_amdgcn_mfma_f32_16x16x32_bf16(a, b, c, 0, 0, 0);
}
// exact floor(sqrt(x^2+y^2)) ring id for pixel p
__device__ __forceinline__ int ring_of(int p) {
    int i = p >> 9, j = p & 511;
    int x = i - 256, y = j - 256;
    int r2 = x * x + y * y;
    int R = (int)sqrtf((float)r2);
    while ((R + 1) * (R + 1) <= r2) R++;
    while (R * R > r2) R--;
    return R;
}

// ---------------- K0: build bf16 transposed weights [n][k] in ws ----------
// bt layout: mat 0 = W1r-W2r, 1 = W2r, 2 = W1i-W2i, 3 = W2i; each 128x128.
__global__ void k_build_bt(const float* __restrict__ w1r, const float* __restrict__ w1i,
                           const float* __restrict__ w2r, const float* __restrict__ w2i,
                           u16* __restrict__ bt) {
    int n = blockIdx.x, k = threadIdx.x;   // grid 128, block 128
    int src = k * NF + n;
    float a1r = w1r[src], a1i = w1i[src], a2r = w2r[src], a2i = w2i[src];
    int d = n * NF + k;
    bt[0 * 16384 + d] = f2bf(a1r - a2r);
    bt[1 * 16384 + d] = f2bf(a2r);
    bt[2 * 16384 + d] = f2bf(a1i - a2i);
    bt[3 * 16384 + d] = f2bf(a2i);
}

// ---------------- K1: masked complex GEMM -> y into d_out -----------------
// block tile 128 px x 128 f, 4 waves (wave = 32 px x 128 f), K=128, BK=32.
// LDS rows padded to 40 ushorts (80 B): conflict-free ds_read_b128.
#define BROW 40
#define LDS_AR 0
#define LDS_AI 5120
#define LDS_B  10240   // + mat*5120

__global__ __launch_bounds__(256, 2) void k_gemm(
    const float* __restrict__ xr, const float* __restrict__ xi,
    const int* __restrict__ mask, const u16* __restrict__ bt,
    float* __restrict__ out)
{
    __shared__ u16 lds[30720];  // 60 KB
    const int t = threadIdx.x;
    const int pbase = blockIdx.x * 128;
    const int w = t >> 6, lane = t & 63;
    const int quad = lane >> 4, l16 = lane & 15;

    floatx4 accRe[2][8], accIm[2][8];
#pragma unroll
    for (int mi = 0; mi < 2; mi++)
#pragma unroll
        for (int ni = 0; ni < 8; ni++) {
            accRe[mi][ni] = (floatx4)0.0f;
            accIm[mi][ni] = (floatx4)0.0f;
        }

    // per-lane row masks for the A fragments (row is lane-uniform in a frag)
    bool uu[2];
    uu[0] = (mask[pbase + w * 32 + l16] == 0);
    uu[1] = (mask[pbase + w * 32 + 16 + l16] == 0);

    // staging mapping: thread -> (row, half of 32-k window)
    const int sr = t >> 1, sh = t & 1;
    const float4* xr4 = (const float4*)(xr + (size_t)(pbase + sr) * NF);
    const float4* xi4 = (const float4*)(xi + (size_t)(pbase + sr) * NF);

    for (int kw = 0; kw < 4; kw++) {
        if (kw) __syncthreads();
        // ---- stage A (unmasked re/im), fp32 -> bf16 ----
        {
            int qb = kw * 8 + sh * 4;
            float4 r0 = xr4[qb], r1 = xr4[qb + 1], r2 = xr4[qb + 2], r3 = xr4[qb + 3];
            float4 i0 = xi4[qb], i1 = xi4[qb + 1], i2 = xi4[qb + 2], i3 = xi4[qb + 3];
            uint4 a, b;
            a.x = pk(r0.x, r0.y); a.y = pk(r0.z, r0.w); a.z = pk(r1.x, r1.y); a.w = pk(r1.z, r1.w);
            b.x = pk(r2.x, r2.y); b.y = pk(r2.z, r2.w); b.z = pk(r3.x, r3.y); b.w = pk(r3.z, r3.w);
            *(uint4*)&lds[LDS_AR + sr * BROW + sh * 16]     = a;
            *(uint4*)&lds[LDS_AR + sr * BROW + sh * 16 + 8] = b;
            a.x = pk(i0.x, i0.y); a.y = pk(i0.z, i0.w); a.z = pk(i1.x, i1.y); a.w = pk(i1.z, i1.w);
            b.x = pk(i2.x, i2.y); b.y = pk(i2.z, i2.w); b.z = pk(i3.x, i3.y); b.w = pk(i3.z, i3.w);
            *(uint4*)&lds[LDS_AI + sr * BROW + sh * 16]     = a;
            *(uint4*)&lds[LDS_AI + sr * BROW + sh * 16 + 8] = b;
        }
        // ---- stage B window (already bf16 in ws, L2-hot) ----
#pragma unroll
        for (int q = 0; q < 8; q++) {
            int fi = q * 256 + t;            // 0..2047
            int mat = fi >> 9;
            int wi = fi & 511;
            int n = wi >> 2, kc = wi & 3;
            uint4 v = *(const uint4*)(bt + mat * 16384 + n * 128 + kw * 32 + kc * 8);
            *(uint4*)&lds[LDS_B + mat * 5120 + n * BROW + kc * 8] = v;
        }
        __syncthreads();

        // ---- compute ----
        short8 ar[2], ai[2], aru[2], aiu[2];
#pragma unroll
        for (int mi = 0; mi < 2; mi++) {
            int r = w * 32 + mi * 16 + l16;
            ar[mi] = *(short8*)&lds[LDS_AR + r * BROW + quad * 8];
            ai[mi] = *(short8*)&lds[LDS_AI + r * BROW + quad * 8];
            aru[mi] = uu[mi] ? ar[mi] : (short8)0;
            aiu[mi] = uu[mi] ? ai[mi] : (short8)0;
        }
#pragma unroll
        for (int ni = 0; ni < 8; ni++) {
            int nrow = ni * 16 + l16;
            short8 bDr = *(short8*)&lds[LDS_B + 0 * 5120 + nrow * BROW + quad * 8];
            short8 b2r = *(short8*)&lds[LDS_B + 1 * 5120 + nrow * BROW + quad * 8];
            short8 bDi = *(short8*)&lds[LDS_B + 2 * 5120 + nrow * BROW + quad * 8];
            short8 b2i = *(short8*)&lds[LDS_B + 3 * 5120 + nrow * BROW + quad * 8];
            short8 bDin = negbf(bDi), b2in = negbf(b2i);
#pragma unroll
            for (int mi = 0; mi < 2; mi++) {
                accRe[mi][ni] = mfma16(aru[mi], bDr,  accRe[mi][ni]);
                accRe[mi][ni] = mfma16(ar[mi],  b2r,  accRe[mi][ni]);
                accRe[mi][ni] = mfma16(aiu[mi], bDin, accRe[mi][ni]);
                accRe[mi][ni] = mfma16(ai[mi],  b2in, accRe[mi][ni]);
                accIm[mi][ni] = mfma16(aru[mi], bDi,  accIm[mi][ni]);
                accIm[mi][ni] = mfma16(ar[mi],  b2i,  accIm[mi][ni]);
                accIm[mi][ni] = mfma16(aiu[mi], bDr,  accIm[mi][ni]);
                accIm[mi][ni] = mfma16(ai[mi],  b2r,  accIm[mi][ni]);
            }
        }
    }

    // ---- epilogue: interleaved [p][f][re,im] float2 stores ----
#pragma unroll
    for (int mi = 0; mi < 2; mi++)
#pragma unroll
        for (int ni = 0; ni < 8; ni++)
#pragma unroll
            for (int r = 0; r < 4; r++) {
                int p = pbase + w * 32 + mi * 16 + quad * 4 + r;
                int f = ni * 16 + l16;
                float2 v;
                v.x = accRe[mi][ni][r];
                v.y = accIm[mi][ni][r];
                *(float2*)(out + (size_t)p * 256 + f * 2) = v;
            }
}

// ---------------- K2a: bucket pixels by ring ------------------------------
// Every pixel bumps total ring count (reference denominator = FULL ring
// size). mask==0 pixels append their id to the ring's fixed-size slab.
__global__ void k_scatter(const int* __restrict__ mask, int* __restrict__ ctr,
                          int* __restrict__ totcnt, int* __restrict__ list)
{
    int p = blockIdx.x * 256 + threadIdx.x;
    int R = ring_of(p);
    atomicAdd(&totcnt[R], 1);
    if (mask[p] == 0) {
        int slot = atomicAdd(&ctr[R], 1);
        list[R * SLAB + slot] = p;
    }
}

// ---------------- K2b: balanced per-ring sums -----------------------------
// block = (ring R, chunk of 128 listed pixels); 256 threads own one column
// each of the interleaved [f][re,im] row. Unconditional coalesced loads.
__global__ __launch_bounds__(256) void k_ringsum2(
    const float* __restrict__ y, const int* __restrict__ ctr,
    const int* __restrict__ list, float* __restrict__ rs)
{
    const int R = blockIdx.x;
    const int nu = ctr[R];
    const int s0 = blockIdx.y * 128;
    if (s0 >= nu) return;
    const int n = min(128, nu - s0);
    __shared__ int sl[128];
    const int t = threadIdx.x;
    if (t < 128) sl[t] = (t < n) ? list[R * SLAB + s0 + t] : 0;
    __syncthreads();
    float acc = 0.0f;
#pragma unroll 4
    for (int k = 0; k < n; k++) {
        int p = sl[k];
        acc += y[(size_t)p * 256 + t];
    }
    atomicAdd(&rs[R * 256 + t], acc);
}

// ---------------- K3: in-place finalize -----------------------------------
__global__ void k_final(const int* __restrict__ mask, const float* __restrict__ rs,
                        const int* __restrict__ totcnt, float* __restrict__ out)
{
    const int t = threadIdx.x;
    const int p0 = blockIdx.x * 64;
    for (int pp = 0; pp < 64; pp++) {
        int p = p0 + pp;
        int R = ring_of(p);
        float c = (float)totcnt[R];
        c = (c < 1.0f) ? 1.0f : c;
        float s = rs[R * 256 + t] / c;
        float v = out[(size_t)p * 256 + t];
        float o = (mask[p] == 0) ? 0.5f * (v + s) : (v - s);
        out[(size_t)p * 256 + t] = o;
    }
}

extern "C" void kernel_launch(void* const* d_in, const int* in_sizes, int n_in,
                              void* d_out, int out_size, void* d_ws, size_t ws_size,
                              hipStream_t stream)
{
    const float* xr  = (const float*)d_in[0];  // image_re [512,512,128]
    const float* xi  = (const float*)d_in[1];  // image_im
    const int*   msk = (const int*)d_in[2];    // mask [512,512] int32
    // d_in[3], d_in[4] = output_re/output_im zero inits (unused)
    const float* w1r = (const float*)d_in[5];
    const float* w1i = (const float*)d_in[6];
    const float* w2r = (const float*)d_in[7];
    const float* w2i = (const float*)d_in[8];
    float* out = (float*)d_out;                // [512,512,128,2] fp32

    // ws layout (bytes):
    //   rs     [363*256] f32 @ 0        (371,712)
    //   ctr    [363]     i32 @ 371,712
    //   totcnt [363]     i32 @ 373,248
    //   list   [363*SLAB] i32 @ 374,784 (2,416,128)
    //   bt     [4*16384] bf16 @ 2,790,912 (131,072)  -> total ~2.92 MB
    char* wsb = (char*)d_ws;
    float* rs     = (float*)(wsb + 0);
    int*   ctr    = (int*)(wsb + 371712);
    int*   totcnt = (int*)(wsb + 373248);
    int*   list   = (int*)(wsb + 374784);
    u16*   bt     = (u16*)(wsb + 2790912);

    hipMemsetAsync(d_ws, 0, 374784, stream);  // rs + ctr + totcnt
    k_build_bt<<<dim3(128), dim3(128), 0, stream>>>(w1r, w1i, w2r, w2i, bt);
    k_gemm<<<dim3(NPIX / 128), dim3(256), 0, stream>>>(xr, xi, msk, bt, out);
    k_scatter<<<dim3(NPIX / 256), dim3(256), 0, stream>>>(msk, ctr, totcnt, list);
    k_ringsum2<<<dim3(NRINGS, 13), dim3(256), 0, stream>>>(out, ctr, list, rs);
    k_final<<<dim3(NPIX / 64), dim3(256), 0, stream>>>(msk, rs, totcnt, out);
}